// Round 13
// baseline (417.341 us; speedup 1.0000x reference)
//
#include <hip/hip_runtime.h>

// ---------------- problem constants ----------------
#define Bn 4
#define Sn 2048
#define Dn 1024
#define Hn 16
#define DKn 64
#define DFFn 4096
#define Mn (Bn * Sn) // 8192
#define QKVS 3072    // fused QKV row stride

typedef __bf16 bf16;
typedef __attribute__((ext_vector_type(8))) __bf16 bf16x8;
typedef __attribute__((ext_vector_type(4))) __bf16 bf16x4;
typedef __attribute__((ext_vector_type(8))) unsigned short u16x8;
typedef __attribute__((ext_vector_type(4))) float f32x4;
typedef __attribute__((ext_vector_type(16))) float f32x16;

#define LOG2E_DIV8 0.18033688011112042f  // 0.125 * log2(e)

__device__ __forceinline__ float exp2fast(float x) {
  return __builtin_amdgcn_exp2f(x);
}

// async global->LDS, 16B per lane; LDS dest = wave-uniform base + lane*16
__device__ __forceinline__ void glds16(const bf16* g, bf16* l) {
  __builtin_amdgcn_global_load_lds((const __attribute__((address_space(1))) void*)g,
                                   (__attribute__((address_space(3))) void*)l, 16, 0, 0);
}

__device__ __forceinline__ unsigned int pkbf16(float a, float b) {
  union { __bf16 h[2]; unsigned int u; } x;
  x.h[0] = (__bf16)a; x.h[1] = (__bf16)b;
  return x.u;
}

// B-row permutation within each 256-row block (8ph kernel layout)
__device__ __host__ __forceinline__ int bperm(int nl) {
  int wn = nl >> 6, rem = nl & 63, nf = rem >> 4, l = rem & 15;
  return ((nf >> 1) << 7) + (wn << 5) + ((nf & 1) << 4) + l;
}

// ---------------- f32 -> bf16 pack ----------------
__global__ __launch_bounds__(256) void k_cvt_bf16(const float* __restrict__ in,
                                                  bf16* __restrict__ out) {
  size_t i = ((size_t)blockIdx.x * 256 + threadIdx.x) * 8;
  f32x4 a = *(const f32x4*)(in + i);
  f32x4 b = *(const f32x4*)(in + i + 4);
  bf16x8 o;
#pragma unroll
  for (int j = 0; j < 4; ++j) { o[j] = (bf16)a[j]; o[j + 4] = (bf16)b[j]; }
  *(bf16x8*)(out + i) = o;
}

// ---------------- merged prep: weight transposes (+B-perm for 8ph users) + biases ----------------
__global__ __launch_bounds__(256) void k_prep(const float* __restrict__ Wq,
                                              const float* __restrict__ Wk,
                                              const float* __restrict__ Wv,
                                              const float* __restrict__ Wo,
                                              const float* __restrict__ W1,
                                              const float* __restrict__ W2,
                                              const float* __restrict__ bq,
                                              const float* __restrict__ bk,
                                              const float* __restrict__ bv,
                                              bf16* __restrict__ wqkvT,
                                              bf16* __restrict__ woT,
                                              bf16* __restrict__ w1T,
                                              bf16* __restrict__ w2T,
                                              float* __restrict__ bqkv) {
  __shared__ float tile[32][33];
  const int id = blockIdx.x, t = threadIdx.x;
  if (id >= 12288) {  // bias concat
    int j = (id - 12288) * 256 + t;
    float v = (j < 1024) ? bq[j] * LOG2E_DIV8
            : (j < 2048) ? bk[j - 1024] : bv[j - 2048];
    bqkv[j] = v;
    return;
  }
  const float* in;
  bf16* out;
  int K, N, bx, by, perm;
  float scale = 1.f;
  if (id < 4096) {
    int z = id >> 10, local = id & 1023;
    bx = local & 31; by = local >> 5;
    K = Dn; N = Dn;
    if (z == 0)      { in = Wq; out = wqkvT; scale = LOG2E_DIV8; perm = 1; }
    else if (z == 1) { in = Wk; out = wqkvT + (size_t)1024 * Dn; perm = 1; }
    else if (z == 2) { in = Wv; out = wqkvT + (size_t)2048 * Dn; perm = 1; }
    else             { in = Wo; out = woT; perm = 0; }
  } else if (id < 8192) {
    int local = id - 4096;
    bx = local & 127; by = local >> 7;
    K = Dn; N = DFFn; in = W1; out = w1T; perm = 1;
  } else {
    int local = id - 8192;
    bx = local & 31; by = local >> 5;
    K = DFFn; N = Dn; in = W2; out = w2T; perm = 0;
  }
  const int n0 = bx * 32, k0 = by * 32;
  const int tx = t & 31, ty = t >> 5;
#pragma unroll
  for (int j = ty; j < 32; j += 8)
    tile[j][tx] = in[(size_t)(k0 + j) * N + n0 + tx];
  __syncthreads();
#pragma unroll
  for (int j = ty; j < 32; j += 8) {
    int row = n0 + j;
    if (perm) row = (row & ~255) | bperm(row & 255);
    out[(size_t)row * K + k0 + tx] = (bf16)(tile[tx][j] * scale);
  }
}

// ---------------- V transpose ----------------
__global__ __launch_bounds__(256) void k_vt(const bf16* __restrict__ v,
                                            bf16* __restrict__ vT, int vs) {
  __shared__ bf16 T[64][72];
  const int t = threadIdx.x;
  const int s0 = blockIdx.x * 64;
  const int bh = blockIdx.y, b = bh >> 4, h = bh & 15;
#pragma unroll
  for (int it = 0; it < 2; ++it) {
    int r = (t >> 3) + it * 32;
    int c = t & 7;
    u16x8 val = *(const u16x8*)(v + (size_t)(b * Sn + s0 + r) * vs + h * 64 + c * 8);
    *(u16x8*)&T[r][c * 8] = val;
  }
  __syncthreads();
#pragma unroll
  for (int it = 0; it < 2; ++it) {
    int d = (t >> 3) + it * 32;
    int cs = t & 7;
    bf16x8 o;
#pragma unroll
    for (int j = 0; j < 8; ++j) o[j] = T[cs * 8 + j][d];
    *(bf16x8*)(vT + ((size_t)bh * 64 + d) * Sn + s0 + cs * 8) = o;
  }
}

// ---------------- 8-phase 256x256 GEMM (R12-verified) ----------------
template <int DO_RELU>
__global__ __launch_bounds__(512, 2) void k_gemm8ph(const bf16* __restrict__ A,
                                                    const bf16* __restrict__ BT,
                                                    const float* __restrict__ bias,
                                                    bf16* __restrict__ C,
                                                    int Ndim, int Kdim) {
  __shared__ __align__(128) bf16 Asm[2][256 * 64];
  __shared__ __align__(128) bf16 Bsm[2][256 * 64];
  const int tid = threadIdx.x;
  const int wid = tid >> 6, lane = tid & 63;
  const int l15 = lane & 15, l4 = lane >> 4;
  const int wm = wid >> 2, wn = wid & 3;

  const int gx = gridDim.x;
  int lin = blockIdx.y * gx + blockIdx.x;
  const int nwg = gx * gridDim.y;
  lin = (lin & 7) * (nwg >> 3) + (lin >> 3);
  const int m0 = (lin / gx) * 256;
  const int n0 = (lin % gx) * 256;

  f32x4 acc[8][4];
#pragma unroll
  for (int mf = 0; mf < 8; ++mf)
#pragma unroll
    for (int nf = 0; nf < 4; ++nf) acc[mf][nf] = f32x4{0.f, 0.f, 0.f, 0.f};

  const int lr = lane >> 3, lc = lane & 7;
  const int NT = Kdim >> 6;
  const int ch0 = lc ^ lr;

#define STGA(buf, t, it)                                                          \
  glds16(A + (size_t)(m0 + (it) * 64 + wid * 8 + lr) * Kdim + (size_t)(t) * 64 +  \
             ch0 * 8,                                                             \
         &Asm[buf][((it) * 64 + wid * 8) * 64]);
#define STGB(buf, t, it)                                                          \
  glds16(BT + (size_t)(n0 + (it) * 64 + wid * 8 + lr) * Kdim + (size_t)(t) * 64 + \
              ch0 * 8,                                                            \
         &Bsm[buf][((it) * 64 + wid * 8) * 64]);

  STGA(0, 0, 0); STGA(0, 0, 2);
  STGB(0, 0, 0); STGB(0, 0, 1);
  STGA(0, 0, 1); STGA(0, 0, 3);
  STGB(0, 0, 2); STGB(0, 0, 3);

  bf16x8 af[4][2], bl[2][2], bh2[2][2];

  for (int j = 0; j < NT; ++j) {
    const int d = j & 1, nb = d ^ 1;
    const bool st = (j + 1 < NT);

    // ---- phase 0 ----
    asm volatile("s_waitcnt vmcnt(4)" ::: "memory");
    __builtin_amdgcn_sched_barrier(0);
    __builtin_amdgcn_s_barrier();
#pragma unroll
    for (int mf = 0; mf < 4; ++mf)
#pragma unroll
      for (int kk = 0; kk < 2; ++kk) {
        int row = wm * 128 + mf * 16 + l15;
        int ch = (kk * 4 + l4) ^ (row & 7);
        af[mf][kk] = *(const bf16x8*)&Asm[d][row * 64 + ch * 8];
      }
#pragma unroll
    for (int nf = 0; nf < 2; ++nf)
#pragma unroll
      for (int kk = 0; kk < 2; ++kk) {
        int row = wn * 32 + nf * 16 + l15;
        int ch = (kk * 4 + l4) ^ (row & 7);
        bl[nf][kk] = *(const bf16x8*)&Bsm[d][row * 64 + ch * 8];
      }
    if (st) { STGA(nb, j + 1, 0); STGA(nb, j + 1, 2); }
    __builtin_amdgcn_s_setprio(1);
#pragma unroll
    for (int mf = 0; mf < 4; ++mf)
#pragma unroll
      for (int nf = 0; nf < 2; ++nf)
#pragma unroll
        for (int kk = 0; kk < 2; ++kk)
          acc[mf][nf] = __builtin_amdgcn_mfma_f32_16x16x32_bf16(af[mf][kk], bl[nf][kk],
                                                                acc[mf][nf], 0, 0, 0);
    __builtin_amdgcn_s_setprio(0);

    // ---- phase 1 ----
    if (st) asm volatile("s_waitcnt vmcnt(4)" ::: "memory");
    else    asm volatile("s_waitcnt vmcnt(2)" ::: "memory");
    __builtin_amdgcn_sched_barrier(0);
    __builtin_amdgcn_s_barrier();
#pragma unroll
    for (int mf = 0; mf < 4; ++mf)
#pragma unroll
      for (int kk = 0; kk < 2; ++kk) {
        int row = wm * 128 + 64 + mf * 16 + l15;
        int ch = (kk * 4 + l4) ^ (row & 7);
        af[mf][kk] = *(const bf16x8*)&Asm[d][row * 64 + ch * 8];
      }
    if (st) { STGB(nb, j + 1, 0); STGB(nb, j + 1, 1); }
    __builtin_amdgcn_s_setprio(1);
#pragma unroll
    for (int mf = 0; mf < 4; ++mf)
#pragma unroll
      for (int nf = 0; nf < 2; ++nf)
#pragma unroll
        for (int kk = 0; kk < 2; ++kk)
          acc[4 + mf][nf] = __builtin_amdgcn_mfma_f32_16x16x32_bf16(af[mf][kk], bl[nf][kk],
                                                                    acc[4 + mf][nf], 0, 0, 0);
    __builtin_amdgcn_s_setprio(0);

    // ---- phase 2 ----
    if (st) asm volatile("s_waitcnt vmcnt(4)" ::: "memory");
    else    asm volatile("s_waitcnt vmcnt(0)" ::: "memory");
    __builtin_amdgcn_sched_barrier(0);
    __builtin_amdgcn_s_barrier();
#pragma unroll
    for (int nf = 0; nf < 2; ++nf)
#pragma unroll
      for (int kk = 0; kk < 2; ++kk) {
        int row = 128 + wn * 32 + nf * 16 + l15;
        int ch = (kk * 4 + l4) ^ (row & 7);
        bh2[nf][kk] = *(const bf16x8*)&Bsm[d][row * 64 + ch * 8];
      }
    if (st) { STGA(nb, j + 1, 1); STGA(nb, j + 1, 3); }
    __builtin_amdgcn_s_setprio(1);
#pragma unroll
    for (int mf = 0; mf < 4; ++mf)
#pragma unroll
      for (int nf = 0; nf < 2; ++nf)
#pragma unroll
        for (int kk = 0; kk < 2; ++kk)
          acc[4 + mf][2 + nf] = __builtin_amdgcn_mfma_f32_16x16x32_bf16(
              af[mf][kk], bh2[nf][kk], acc[4 + mf][2 + nf], 0, 0, 0);
    __builtin_amdgcn_s_setprio(0);

    // ---- phase 3 ----
#pragma unroll
    for (int mf = 0; mf < 4; ++mf)
#pragma unroll
      for (int kk = 0; kk < 2; ++kk) {
        int row = wm * 128 + mf * 16 + l15;
        int ch = (kk * 4 + l4) ^ (row & 7);
        af[mf][kk] = *(const bf16x8*)&Asm[d][row * 64 + ch * 8];
      }
    if (st) { STGB(nb, j + 1, 2); STGB(nb, j + 1, 3); }
    __builtin_amdgcn_s_setprio(1);
#pragma unroll
    for (int mf = 0; mf < 4; ++mf)
#pragma unroll
      for (int nf = 0; nf < 2; ++nf)
#pragma unroll
        for (int kk = 0; kk < 2; ++kk)
          acc[mf][2 + nf] = __builtin_amdgcn_mfma_f32_16x16x32_bf16(
              af[mf][kk], bh2[nf][kk], acc[mf][2 + nf], 0, 0, 0);
    __builtin_amdgcn_s_setprio(0);
  }
#undef STGA
#undef STGB

#pragma unroll
  for (int mf = 0; mf < 8; ++mf)
#pragma unroll
    for (int nf = 0; nf < 4; ++nf) {
      int c = n0 + wn * 64 + nf * 16 + l15;
      float bv = bias[c];
      int r0 = m0 + wm * 128 + mf * 16 + l4 * 4;
#pragma unroll
      for (int r = 0; r < 4; ++r) {
        float val = acc[mf][nf][r] + bv;
        if (DO_RELU) val = fmaxf(val, 0.f);
        C[(size_t)(r0 + r) * Ndim + c] = (bf16)val;
      }
    }
}

// ---------------- 256-row MFMA GEMM, counted-vmcnt pipeline (R5-verified; N=1024 shapes) ----------------
template <int NFRAG, int DO_RELU>
__global__ __launch_bounds__(512, 2) void k_gemm256(const bf16* __restrict__ A,
                                                    const bf16* __restrict__ BT,
                                                    const float* __restrict__ bias,
                                                    bf16* __restrict__ C,
                                                    int Ndim, int Kdim) {
  __shared__ __align__(128) bf16 Asm[2][256 * 64];
  __shared__ __align__(128) bf16 Bsm[2][NFRAG * 64 * 64];
  const int tid = threadIdx.x;
  const int wid = tid >> 6, lane = tid & 63;
  const int l15 = lane & 15, l4 = lane >> 4;
  const int wm = wid >> 2, wn = wid & 3;

  const int gx = gridDim.x;
  int lin = blockIdx.y * gx + blockIdx.x;
  const int nwg = gx * gridDim.y;
  lin = (lin & 7) * (nwg >> 3) + (lin >> 3);
  const int m0 = (lin / gx) * 256;
  const int n0 = (lin % gx) * (NFRAG * 64);

  f32x4 acc[8][NFRAG];
#pragma unroll
  for (int mf = 0; mf < 8; ++mf)
#pragma unroll
    for (int nf = 0; nf < NFRAG; ++nf) acc[mf][nf] = f32x4{0.f, 0.f, 0.f, 0.f};

  const int lr = lane >> 3, lc = lane & 7;
  const int NT = Kdim >> 6;

#define STAGE(buf, t)                                                              \
  {                                                                                \
    _Pragma("unroll") for (int it = 0; it < 4; ++it) {                             \
      int r = it * 64 + wid * 8 + lr;                                              \
      int ch = lc ^ (r & 7);                                                       \
      glds16(A + (size_t)(m0 + r) * Kdim + (size_t)(t) * 64 + ch * 8,              \
             &Asm[buf][(it * 64 + wid * 8) * 64]);                                 \
    }                                                                              \
    _Pragma("unroll") for (int it = 0; it < NFRAG; ++it) {                         \
      int r = it * 64 + wid * 8 + lr;                                              \
      int ch = lc ^ (r & 7);                                                       \
      glds16(BT + (size_t)(n0 + r) * Kdim + (size_t)(t) * 64 + ch * 8,             \
             &Bsm[buf][(it * 64 + wid * 8) * 64]);                                 \
    }                                                                              \
  }

  int p = 0;
  STAGE(0, 0);
  for (int t = 0; t < NT; ++t) {
    if (t + 1 < NT) {
      STAGE(p ^ 1, t + 1);
      if constexpr (NFRAG == 4) asm volatile("s_waitcnt vmcnt(8)" ::: "memory");
      else                      asm volatile("s_waitcnt vmcnt(6)" ::: "memory");
    } else {
      asm volatile("s_waitcnt vmcnt(0)" ::: "memory");
    }
    __builtin_amdgcn_sched_barrier(0);
    __builtin_amdgcn_s_barrier();

    bf16x8 bfrag[NFRAG][2];
#pragma unroll
    for (int nf = 0; nf < NFRAG; ++nf)
#pragma unroll
      for (int kk = 0; kk < 2; ++kk) {
        int r = wn * (NFRAG * 16) + nf * 16 + l15;
        int ch = (kk * 4 + l4) ^ (r & 7);
        bfrag[nf][kk] = *(const bf16x8*)&Bsm[p][r * 64 + ch * 8];
      }
#pragma unroll
    for (int half = 0; half < 2; ++half) {
      bf16x8 afr[4][2];
#pragma unroll
      for (int mf4 = 0; mf4 < 4; ++mf4)
#pragma unroll
        for (int kk = 0; kk < 2; ++kk) {
          int r = wm * 128 + half * 64 + mf4 * 16 + l15;
          int ch = (kk * 4 + l4) ^ (r & 7);
          afr[mf4][kk] = *(const bf16x8*)&Asm[p][r * 64 + ch * 8];
        }
      __builtin_amdgcn_s_setprio(1);
#pragma unroll
      for (int mf4 = 0; mf4 < 4; ++mf4)
#pragma unroll
        for (int nf = 0; nf < NFRAG; ++nf)
#pragma unroll
          for (int kk = 0; kk < 2; ++kk)
            acc[half * 4 + mf4][nf] = __builtin_amdgcn_mfma_f32_16x16x32_bf16(
                afr[mf4][kk], bfrag[nf][kk], acc[half * 4 + mf4][nf], 0, 0, 0);
      __builtin_amdgcn_s_setprio(0);
    }
    __builtin_amdgcn_s_barrier();
    p ^= 1;
  }
#undef STAGE

#pragma unroll
  for (int mf = 0; mf < 8; ++mf)
#pragma unroll
    for (int nf = 0; nf < NFRAG; ++nf) {
      int c = n0 + wn * (NFRAG * 16) + nf * 16 + l15;
      float bv = bias[c];
      int r0 = m0 + wm * 128 + mf * 16 + l4 * 4;
#pragma unroll
      for (int r = 0; r < 4; ++r) {
        float val = acc[mf][nf][r] + bv;
        if (DO_RELU) val = fmaxf(val, 0.f);
        C[(size_t)(r0 + r) * Ndim + c] = (bf16)val;
      }
    }
}

// ---------------- flash attention, split-KV x2 ----------------
// grid (16, 64): x = qblk(8) x half(2); 512 thr (8 waves), wave owns 32 q rows.
// Each block processes KV rows [half*1024, +1024) = 16 tiles, writes UNNORMALIZED
// bf16 O-partial + per-row (m,l). k_combine merges halves. 1024 blocks -> 4/CU.
__global__ __launch_bounds__(512) void k_attn(const bf16* __restrict__ q,
                                              const bf16* __restrict__ k,
                                              const bf16* __restrict__ vT,
                                              const int* __restrict__ mask,
                                              bf16* __restrict__ opart,
                                              float2* __restrict__ ml, int qs) {
  __shared__ __align__(128) bf16 Kt[2][64 * 64];
  __shared__ __align__(128) bf16 Vt[2][64 * 64];
  __shared__ float Mb[Sn];
  const int tid = threadIdx.x, wid = tid >> 6, lane = tid & 63;
  const int q31 = lane & 31, hi = lane >> 5;

  int lin = blockIdx.y * gridDim.x + blockIdx.x;  // 1024 blocks
  lin = (lin & 7) * 128 + (lin >> 3);
  const int xq = lin & 15, bh = lin >> 4;
  const int half = xq & 1, qblk = xq >> 1;
  const int b = bh >> 4, h = bh & 15;
  const int q0 = qblk * 256 + wid * 32;
  const int kv0 = half * 16;  // first KV tile index

  for (int i = tid; i < Sn; i += 512)
    Mb[i] = mask[b * Sn + i] ? 0.f : -1.44269504e9f;

  bf16x8 qf[4];
#pragma unroll
  for (int t = 0; t < 4; ++t)
    qf[t] = *(const bf16x8*)(q + (size_t)(b * Sn + q0 + q31) * qs + h * 64 +
                             t * 16 + hi * 8);

  f32x16 o[2];
  o[0] = {}; o[1] = {};
  float mr = -INFINITY, lr = 0.f;

  const int lrow = lane >> 3;
  const int lch0 = lane & 7;
  const int sch = lch0 ^ (lrow ^ (wid & 3));

  for (int t16 = 0; t16 < 16; ++t16) {
    const int kb = kv0 + t16;
    const int cur = t16 & 1;
    if (t16 == 0) {
      int row = wid * 8 + lrow;
      glds16(k + (size_t)(b * Sn + kb * 64 + row) * qs + h * 64 + sch * 8,
             &Kt[0][wid * 512]);
      glds16(vT + ((size_t)bh * 64 + row) * Sn + kb * 64 + sch * 8, &Vt[0][wid * 512]);
      __syncthreads();
    }
    if (t16 + 1 < 16) {
      int row = wid * 8 + lrow;
      glds16(k + (size_t)(b * Sn + (kb + 1) * 64 + row) * qs + h * 64 + sch * 8,
             &Kt[cur ^ 1][wid * 512]);
      glds16(vT + ((size_t)bh * 64 + row) * Sn + (kb + 1) * 64 + sch * 8,
             &Vt[cur ^ 1][wid * 512]);
    }

    f32x16 sc[2];
#pragma unroll
    for (int kf = 0; kf < 2; ++kf)
#pragma unroll
      for (int rg = 0; rg < 4; ++rg) {
        f32x4 mb4 = *(const f32x4*)&Mb[kb * 64 + kf * 32 + rg * 8 + 4 * hi];
#pragma unroll
        for (int j = 0; j < 4; ++j) sc[kf][rg * 4 + j] = mb4[j];
      }
#pragma unroll
    for (int t = 0; t < 4; ++t) {
#pragma unroll
      for (int kf = 0; kf < 2; ++kf) {
        int row = kf * 32 + q31;
        int ch = (t * 2 + hi) ^ ((row & 7) ^ ((row >> 3) & 3));
        bf16x8 kfr = *(const bf16x8*)&Kt[cur][row * 64 + ch * 8];
        sc[kf] = __builtin_amdgcn_mfma_f32_32x32x16_bf16(kfr, qf[t], sc[kf], 0, 0, 0);
      }
    }

    float rmax = fmaxf(sc[0][0], sc[0][1]);
#pragma unroll
    for (int i = 2; i < 16; i += 2)
      rmax = fmaxf(fmaxf(rmax, sc[0][i]), sc[0][i + 1]);
#pragma unroll
    for (int i = 0; i < 16; i += 2)
      rmax = fmaxf(fmaxf(rmax, sc[1][i]), sc[1][i + 1]);
    rmax = fmaxf(rmax, __shfl_xor(rmax, 32));

    if (!__all(rmax <= mr + 8.f)) {
      float mnew = fmaxf(mr, rmax);
      float psc = exp2fast(mr - mnew);
      mr = mnew;
      lr *= psc;
#pragma unroll
      for (int af = 0; af < 2; ++af)
#pragma unroll
        for (int i = 0; i < 16; ++i) o[af][i] *= psc;
    }

    float psum = 0.f;
#pragma unroll
    for (int kf = 0; kf < 2; ++kf)
#pragma unroll
      for (int i = 0; i < 16; ++i) {
        float p = exp2fast(sc[kf][i] - mr);
        sc[kf][i] = p;
        psum += p;
      }
    psum += __shfl_xor(psum, 32);
    lr += psum;

#pragma unroll
    for (int ks = 0; ks < 4; ++ks) {
      const int kf = ks >> 1, R = (ks & 1) * 8;
      unsigned int a0 = pkbf16(sc[kf][R + 0], sc[kf][R + 1]);
      unsigned int a1 = pkbf16(sc[kf][R + 2], sc[kf][R + 3]);
      unsigned int b0 = pkbf16(sc[kf][R + 4], sc[kf][R + 5]);
      unsigned int b1 = pkbf16(sc[kf][R + 6], sc[kf][R + 7]);
      unsigned int sxa0 = __shfl_xor(a0, 32), sxa1 = __shfl_xor(a1, 32);
      unsigned int sxb0 = __shfl_xor(b0, 32), sxb1 = __shfl_xor(b1, 32);
      union { unsigned int w[4]; bf16x8 v; } pfu;
      pfu.w[0] = hi ? sxb0 : a0;
      pfu.w[1] = hi ? sxb1 : a1;
      pfu.w[2] = hi ? b0 : sxa0;
      pfu.w[3] = hi ? b1 : sxa1;
#pragma unroll
      for (int af = 0; af < 2; ++af) {
        int row = af * 32 + q31;
        int ch = (ks * 2 + hi) ^ ((row & 7) ^ ((row >> 3) & 3));
        bf16x8 vfr = *(const bf16x8*)&Vt[cur][row * 64 + ch * 8];
        o[af] = __builtin_amdgcn_mfma_f32_32x32x16_bf16(vfr, pfu.v, o[af], 0, 0, 0);
      }
    }
    __syncthreads();
  }

  // epilogue: unnormalized O partial + (m,l)
  const size_t row = (size_t)(b * Sn + q0 + q31);
  const size_t obase = ((size_t)half * Mn + row) * Dn + h * 64;
#pragma unroll
  for (int af = 0; af < 2; ++af)
#pragma unroll
    for (int rg = 0; rg < 4; ++rg) {
      bf16x4 ov;
#pragma unroll
      for (int j = 0; j < 4; ++j) ov[j] = (bf16)o[af][rg * 4 + j];
      *(bf16x4*)(opart + obase + af * 32 + rg * 8 + 4 * hi) = ov;
    }
  if (lane < 32) ml[((size_t)half * Mn + row) * Hn + h] = float2{mr, lr};
}

// ---------------- split-KV combine: ctx = (a0*O0 + a1*O1) / (a0*l0 + a1*l1) ----------------
__global__ __launch_bounds__(256) void k_combine(const bf16* __restrict__ opart,
                                                 const float2* __restrict__ ml,
                                                 bf16* __restrict__ ctx) {
  int idx = blockIdx.x * 256 + threadIdx.x;  // over Mn*Dn/4
  int row = idx >> 8;        // Dn/4 = 256 chunks per row
  int c4 = idx & 255;
  int h = c4 >> 4;
  float2 m0 = ml[(size_t)row * Hn + h];
  float2 m1 = ml[((size_t)Mn + row) * Hn + h];
  float m = fmaxf(m0.x, m1.x);
  float a0 = exp2fast(m0.x - m), a1 = exp2fast(m1.x - m);
  float inv = 1.f / (a0 * m0.y + a1 * m1.y);
  size_t off = (size_t)row * Dn + c4 * 4;
  bf16x4 o0 = *(const bf16x4*)(opart + off);
  bf16x4 o1 = *(const bf16x4*)(opart + (size_t)Mn * Dn + off);
  bf16x4 o;
#pragma unroll
  for (int j = 0; j < 4; ++j)
    o[j] = (bf16)((a0 * (float)o0[j] + a1 * (float)o1[j]) * inv);
  *(bf16x4*)(ctx + off) = o;
}

// ---------------- residual + LayerNorm (ddof=1, /(std+eps)) ----------------
template <int XF32, int OUTF32>
__global__ __launch_bounds__(256) void k_ln(const void* __restrict__ xp,
                                            const bf16* __restrict__ res,
                                            const float* __restrict__ gamma,
                                            const float* __restrict__ beta,
                                            void* __restrict__ yout) {
  const int row = blockIdx.x, t = threadIdx.x;
  const size_t base = (size_t)row * Dn + t * 4;
  f32x4 a;
  if constexpr (XF32) {
    a = *(const f32x4*)((const float*)xp + base);
  } else {
    bf16x4 x4 = *(const bf16x4*)((const bf16*)xp + base);
#pragma unroll
    for (int j = 0; j < 4; ++j) a[j] = (float)x4[j];
  }
  bf16x4 rb = *(const bf16x4*)(res + base);
  f32x4 vv;
#pragma unroll
  for (int j = 0; j < 4; ++j) vv[j] = a[j] + (float)rb[j];

  float s = vv[0] + vv[1] + vv[2] + vv[3];
#pragma unroll
  for (int off = 32; off; off >>= 1) s += __shfl_xor(s, off);
  __shared__ float red1[4], red2[4];
  if ((t & 63) == 0) red1[t >> 6] = s;
  __syncthreads();
  float mean = (red1[0] + red1[1] + red1[2] + red1[3]) * (1.f / 1024.f);

  float d[4], s2 = 0.f;
#pragma unroll
  for (int j = 0; j < 4; ++j) { d[j] = vv[j] - mean; s2 += d[j] * d[j]; }
#pragma unroll
  for (int off = 32; off; off >>= 1) s2 += __shfl_xor(s2, off);
  if ((t & 63) == 0) red2[t >> 6] = s2;
  __syncthreads();
  float var = (red2[0] + red2[1] + red2[2] + red2[3]) * (1.f / 1023.f);
  float inv = 1.f / (sqrtf(var) + 1e-6f);

  f32x4 g = *(const f32x4*)(gamma + t * 4);
  f32x4 bt = *(const f32x4*)(beta + t * 4);
#pragma unroll
  for (int j = 0; j < 4; ++j) d[j] = g[j] * d[j] * inv + bt[j];
  if constexpr (OUTF32) {
    f32x4 outv = {d[0], d[1], d[2], d[3]};
    *(f32x4*)((float*)yout + base) = outv;
  } else {
    bf16x4 outb;
#pragma unroll
    for (int j = 0; j < 4; ++j) outb[j] = (bf16)d[j];
    *(bf16x4*)((bf16*)yout + base) = outb;
  }
}

// ---------------- host launcher ----------------
extern "C" void kernel_launch(void* const* d_in, const int* in_sizes, int n_in,
                              void* d_out, int out_size, void* d_ws, size_t ws_size,
                              hipStream_t stream) {
  const float* x   = (const float*)d_in[0];
  const int*   msk = (const int*)d_in[1];
  const float* Wq  = (const float*)d_in[2];
  const float* bq  = (const float*)d_in[3];
  const float* Wk  = (const float*)d_in[4];
  const float* bk  = (const float*)d_in[5];
  const float* Wv  = (const float*)d_in[6];
  const float* bv  = (const float*)d_in[7];
  const float* Wo  = (const float*)d_in[8];
  const float* bo  = (const float*)d_in[9];
  const float* W1  = (const float*)d_in[10];
  const float* b1  = (const float*)d_in[11];
  const float* W2  = (const float*)d_in[12];
  const float* b2  = (const float*)d_in[13];
  const float* g1  = (const float*)d_in[14];
  const float* be1 = (const float*)d_in[15];
  const float* g2  = (const float*)d_in[16];
  const float* be2 = (const float*)d_in[17];
  float* out = (float*)d_out;

  char* w = (char*)d_ws;
  size_t off = 0;
  auto alloc = [&](size_t bytes) { void* p = w + off; off += (bytes + 255) & ~(size_t)255; return p; };
  bf16* xb    = (bf16*)alloc((size_t)Mn * Dn * 2);
  bf16* wqkvT = (bf16*)alloc((size_t)QKVS * Dn * 2);
  bf16* woT   = (bf16*)alloc((size_t)Dn * Dn * 2);
  bf16* w1T   = (bf16*)alloc((size_t)Dn * DFFn * 2);
  bf16* w2T   = (bf16*)alloc((size_t)DFFn * Dn * 2);
  float* bqkv = (float*)alloc((size_t)QKVS * 4);
  bf16* qkv   = (bf16*)alloc((size_t)Mn * QKVS * 2);
  bf16* ctx   = (bf16*)alloc((size_t)Mn * Dn * 2);
  bf16* attnb = (bf16*)alloc((size_t)Mn * Dn * 2);
  bf16* yb    = (bf16*)alloc((size_t)Mn * Dn * 2);
  bf16* opart = (bf16*)alloc((size_t)2 * Mn * Dn * 2);     // 32MB split-KV partials
  float2* mlb = (float2*)alloc((size_t)2 * Mn * Hn * 8);   // 2MB (m,l) pairs
  (void)ws_size; (void)in_sizes; (void)n_in; (void)out_size;
  bf16* vT = xb;
  bf16* hh = qkv;
  bf16* ff = xb;

  // 1. pack x; merged weight transposes (+perm) + bias concat
  k_cvt_bf16<<<(Mn * Dn) / 2048, 256, 0, stream>>>(x, xb);
  k_prep<<<12300, 256, 0, stream>>>(Wq, Wk, Wv, Wo, W1, W2, bq, bk, bv,
                                    wqkvT, woT, w1T, w2T, bqkv);

  // 2. fused QKV projection (8-phase, permuted B)
  k_gemm8ph<0><<<dim3(QKVS / 256, Mn / 256), 512, 0, stream>>>(xb, wqkvT, bqkv, qkv, QKVS, Dn);

  // 3. V transpose + flash attention (split-KV x2) + combine
  k_vt<<<dim3(Sn / 64, Bn * Hn), 256, 0, stream>>>(qkv + 2048, vT, QKVS);
  k_attn<<<dim3(16, Bn * Hn), 512, 0, stream>>>(qkv, qkv + 1024, vT, msk, opart, mlb, QKVS);
  k_combine<<<(Mn * Dn / 4) / 256, 256, 0, stream>>>(opart, mlb, ctx);

  // 4. output projection
  k_gemm256<2, 0><<<dim3(Dn / 128, Mn / 256), 512, 0, stream>>>(ctx, woT, bo, attnb, Dn, Dn);

  // 5. LN1
  k_ln<1, 0><<<Mn, 256, 0, stream>>>(x, attnb, g1, be1, yb);

  // 6. FF1 (relu, 8-phase, permuted B)
  k_gemm8ph<1><<<dim3(DFFn / 256, Mn / 256), 512, 0, stream>>>(yb, w1T, b1, hh, DFFn, Dn);

  // 7. FF2
  k_gemm256<2, 0><<<dim3(Dn / 128, Mn / 256), 512, 0, stream>>>(hh, w2T, b2, ff, Dn, DFFn);

  // 8. LN2
  k_ln<0, 1><<<Mn, 256, 0, stream>>>(yb, ff, g2, be2, out);
}

// Round 14
// 388.510 us; speedup vs baseline: 1.0742x; 1.0742x over previous
//
#include <hip/hip_runtime.h>

// ---------------- problem constants ----------------
#define Bn 4
#define Sn 2048
#define Dn 1024
#define Hn 16
#define DKn 64
#define DFFn 4096
#define Mn (Bn * Sn) // 8192
#define QKVS 3072    // fused QKV row stride

typedef __bf16 bf16;
typedef __attribute__((ext_vector_type(8))) __bf16 bf16x8;
typedef __attribute__((ext_vector_type(4))) __bf16 bf16x4;
typedef __attribute__((ext_vector_type(8))) unsigned short u16x8;
typedef __attribute__((ext_vector_type(4))) float f32x4;
typedef __attribute__((ext_vector_type(16))) float f32x16;

#define LOG2E_DIV8 0.18033688011112042f  // 0.125 * log2(e)

__device__ __forceinline__ float exp2fast(float x) {
  return __builtin_amdgcn_exp2f(x);
}

// async global->LDS, 16B per lane; LDS dest = wave-uniform base + lane*16
__device__ __forceinline__ void glds16(const bf16* g, bf16* l) {
  __builtin_amdgcn_global_load_lds((const __attribute__((address_space(1))) void*)g,
                                   (__attribute__((address_space(3))) void*)l, 16, 0, 0);
}

__device__ __forceinline__ unsigned int pkbf16(float a, float b) {
  union { __bf16 h[2]; unsigned int u; } x;
  x.h[0] = (__bf16)a; x.h[1] = (__bf16)b;
  return x.u;
}

// B-row permutation within each 256-row block (8ph kernel layout)
__device__ __host__ __forceinline__ int bperm(int nl) {
  int wn = nl >> 6, rem = nl & 63, nf = rem >> 4, l = rem & 15;
  return ((nf >> 1) << 7) + (wn << 5) + ((nf & 1) << 4) + l;
}

// ---------------- f32 -> bf16 pack ----------------
__global__ __launch_bounds__(256) void k_cvt_bf16(const float* __restrict__ in,
                                                  bf16* __restrict__ out) {
  size_t i = ((size_t)blockIdx.x * 256 + threadIdx.x) * 8;
  f32x4 a = *(const f32x4*)(in + i);
  f32x4 b = *(const f32x4*)(in + i + 4);
  bf16x8 o;
#pragma unroll
  for (int j = 0; j < 4; ++j) { o[j] = (bf16)a[j]; o[j + 4] = (bf16)b[j]; }
  *(bf16x8*)(out + i) = o;
}

// ---------------- merged prep: weight transposes (+B-perm for 8ph users) + biases ----------------
__global__ __launch_bounds__(256) void k_prep(const float* __restrict__ Wq,
                                              const float* __restrict__ Wk,
                                              const float* __restrict__ Wv,
                                              const float* __restrict__ Wo,
                                              const float* __restrict__ W1,
                                              const float* __restrict__ W2,
                                              const float* __restrict__ bq,
                                              const float* __restrict__ bk,
                                              const float* __restrict__ bv,
                                              bf16* __restrict__ wqkvT,
                                              bf16* __restrict__ woT,
                                              bf16* __restrict__ w1T,
                                              bf16* __restrict__ w2T,
                                              float* __restrict__ bqkv) {
  __shared__ float tile[32][33];
  const int id = blockIdx.x, t = threadIdx.x;
  if (id >= 12288) {  // bias concat
    int j = (id - 12288) * 256 + t;
    float v = (j < 1024) ? bq[j] * LOG2E_DIV8
            : (j < 2048) ? bk[j - 1024] : bv[j - 2048];
    bqkv[j] = v;
    return;
  }
  const float* in;
  bf16* out;
  int K, N, bx, by, perm;
  float scale = 1.f;
  if (id < 4096) {
    int z = id >> 10, local = id & 1023;
    bx = local & 31; by = local >> 5;
    K = Dn; N = Dn;
    if (z == 0)      { in = Wq; out = wqkvT; scale = LOG2E_DIV8; perm = 1; }
    else if (z == 1) { in = Wk; out = wqkvT + (size_t)1024 * Dn; perm = 1; }
    else if (z == 2) { in = Wv; out = wqkvT + (size_t)2048 * Dn; perm = 1; }
    else             { in = Wo; out = woT; perm = 0; }
  } else if (id < 8192) {
    int local = id - 4096;
    bx = local & 127; by = local >> 7;
    K = Dn; N = DFFn; in = W1; out = w1T; perm = 1;
  } else {
    int local = id - 8192;
    bx = local & 31; by = local >> 5;
    K = DFFn; N = Dn; in = W2; out = w2T; perm = 0;
  }
  const int n0 = bx * 32, k0 = by * 32;
  const int tx = t & 31, ty = t >> 5;
#pragma unroll
  for (int j = ty; j < 32; j += 8)
    tile[j][tx] = in[(size_t)(k0 + j) * N + n0 + tx];
  __syncthreads();
#pragma unroll
  for (int j = ty; j < 32; j += 8) {
    int row = n0 + j;
    if (perm) row = (row & ~255) | bperm(row & 255);
    out[(size_t)row * K + k0 + tx] = (bf16)(tile[tx][j] * scale);
  }
}

// ---------------- V transpose ----------------
__global__ __launch_bounds__(256) void k_vt(const bf16* __restrict__ v,
                                            bf16* __restrict__ vT, int vs) {
  __shared__ bf16 T[64][72];
  const int t = threadIdx.x;
  const int s0 = blockIdx.x * 64;
  const int bh = blockIdx.y, b = bh >> 4, h = bh & 15;
#pragma unroll
  for (int it = 0; it < 2; ++it) {
    int r = (t >> 3) + it * 32;
    int c = t & 7;
    u16x8 val = *(const u16x8*)(v + (size_t)(b * Sn + s0 + r) * vs + h * 64 + c * 8);
    *(u16x8*)&T[r][c * 8] = val;
  }
  __syncthreads();
#pragma unroll
  for (int it = 0; it < 2; ++it) {
    int d = (t >> 3) + it * 32;
    int cs = t & 7;
    bf16x8 o;
#pragma unroll
    for (int j = 0; j < 8; ++j) o[j] = T[cs * 8 + j][d];
    *(bf16x8*)(vT + ((size_t)bh * 64 + d) * Sn + s0 + cs * 8) = o;
  }
}

// ---------------- 8-phase 256x256 GEMM (R12-verified) ----------------
template <int DO_RELU>
__global__ __launch_bounds__(512, 2) void k_gemm8ph(const bf16* __restrict__ A,
                                                    const bf16* __restrict__ BT,
                                                    const float* __restrict__ bias,
                                                    bf16* __restrict__ C,
                                                    int Ndim, int Kdim) {
  __shared__ __align__(128) bf16 Asm[2][256 * 64];
  __shared__ __align__(128) bf16 Bsm[2][256 * 64];
  const int tid = threadIdx.x;
  const int wid = tid >> 6, lane = tid & 63;
  const int l15 = lane & 15, l4 = lane >> 4;
  const int wm = wid >> 2, wn = wid & 3;

  const int gx = gridDim.x;
  int lin = blockIdx.y * gx + blockIdx.x;
  const int nwg = gx * gridDim.y;
  lin = (lin & 7) * (nwg >> 3) + (lin >> 3);
  const int m0 = (lin / gx) * 256;
  const int n0 = (lin % gx) * 256;

  f32x4 acc[8][4];
#pragma unroll
  for (int mf = 0; mf < 8; ++mf)
#pragma unroll
    for (int nf = 0; nf < 4; ++nf) acc[mf][nf] = f32x4{0.f, 0.f, 0.f, 0.f};

  const int lr = lane >> 3, lc = lane & 7;
  const int NT = Kdim >> 6;
  const int ch0 = lc ^ lr;

#define STGA(buf, t, it)                                                          \
  glds16(A + (size_t)(m0 + (it) * 64 + wid * 8 + lr) * Kdim + (size_t)(t) * 64 +  \
             ch0 * 8,                                                             \
         &Asm[buf][((it) * 64 + wid * 8) * 64]);
#define STGB(buf, t, it)                                                          \
  glds16(BT + (size_t)(n0 + (it) * 64 + wid * 8 + lr) * Kdim + (size_t)(t) * 64 + \
              ch0 * 8,                                                            \
         &Bsm[buf][((it) * 64 + wid * 8) * 64]);

  STGA(0, 0, 0); STGA(0, 0, 2);
  STGB(0, 0, 0); STGB(0, 0, 1);
  STGA(0, 0, 1); STGA(0, 0, 3);
  STGB(0, 0, 2); STGB(0, 0, 3);

  bf16x8 af[4][2], bl[2][2], bh2[2][2];

  for (int j = 0; j < NT; ++j) {
    const int d = j & 1, nb = d ^ 1;
    const bool st = (j + 1 < NT);

    // ---- phase 0 ----
    asm volatile("s_waitcnt vmcnt(4)" ::: "memory");
    __builtin_amdgcn_sched_barrier(0);
    __builtin_amdgcn_s_barrier();
#pragma unroll
    for (int mf = 0; mf < 4; ++mf)
#pragma unroll
      for (int kk = 0; kk < 2; ++kk) {
        int row = wm * 128 + mf * 16 + l15;
        int ch = (kk * 4 + l4) ^ (row & 7);
        af[mf][kk] = *(const bf16x8*)&Asm[d][row * 64 + ch * 8];
      }
#pragma unroll
    for (int nf = 0; nf < 2; ++nf)
#pragma unroll
      for (int kk = 0; kk < 2; ++kk) {
        int row = wn * 32 + nf * 16 + l15;
        int ch = (kk * 4 + l4) ^ (row & 7);
        bl[nf][kk] = *(const bf16x8*)&Bsm[d][row * 64 + ch * 8];
      }
    if (st) { STGA(nb, j + 1, 0); STGA(nb, j + 1, 2); }
    __builtin_amdgcn_s_setprio(1);
#pragma unroll
    for (int mf = 0; mf < 4; ++mf)
#pragma unroll
      for (int nf = 0; nf < 2; ++nf)
#pragma unroll
        for (int kk = 0; kk < 2; ++kk)
          acc[mf][nf] = __builtin_amdgcn_mfma_f32_16x16x32_bf16(af[mf][kk], bl[nf][kk],
                                                                acc[mf][nf], 0, 0, 0);
    __builtin_amdgcn_s_setprio(0);

    // ---- phase 1 ----
    if (st) asm volatile("s_waitcnt vmcnt(4)" ::: "memory");
    else    asm volatile("s_waitcnt vmcnt(2)" ::: "memory");
    __builtin_amdgcn_sched_barrier(0);
    __builtin_amdgcn_s_barrier();
#pragma unroll
    for (int mf = 0; mf < 4; ++mf)
#pragma unroll
      for (int kk = 0; kk < 2; ++kk) {
        int row = wm * 128 + 64 + mf * 16 + l15;
        int ch = (kk * 4 + l4) ^ (row & 7);
        af[mf][kk] = *(const bf16x8*)&Asm[d][row * 64 + ch * 8];
      }
    if (st) { STGB(nb, j + 1, 0); STGB(nb, j + 1, 1); }
    __builtin_amdgcn_s_setprio(1);
#pragma unroll
    for (int mf = 0; mf < 4; ++mf)
#pragma unroll
      for (int nf = 0; nf < 2; ++nf)
#pragma unroll
        for (int kk = 0; kk < 2; ++kk)
          acc[4 + mf][nf] = __builtin_amdgcn_mfma_f32_16x16x32_bf16(af[mf][kk], bl[nf][kk],
                                                                    acc[4 + mf][nf], 0, 0, 0);
    __builtin_amdgcn_s_setprio(0);

    // ---- phase 2 ----
    if (st) asm volatile("s_waitcnt vmcnt(4)" ::: "memory");
    else    asm volatile("s_waitcnt vmcnt(0)" ::: "memory");
    __builtin_amdgcn_sched_barrier(0);
    __builtin_amdgcn_s_barrier();
#pragma unroll
    for (int nf = 0; nf < 2; ++nf)
#pragma unroll
      for (int kk = 0; kk < 2; ++kk) {
        int row = 128 + wn * 32 + nf * 16 + l15;
        int ch = (kk * 4 + l4) ^ (row & 7);
        bh2[nf][kk] = *(const bf16x8*)&Bsm[d][row * 64 + ch * 8];
      }
    if (st) { STGA(nb, j + 1, 1); STGA(nb, j + 1, 3); }
    __builtin_amdgcn_s_setprio(1);
#pragma unroll
    for (int mf = 0; mf < 4; ++mf)
#pragma unroll
      for (int nf = 0; nf < 2; ++nf)
#pragma unroll
        for (int kk = 0; kk < 2; ++kk)
          acc[4 + mf][2 + nf] = __builtin_amdgcn_mfma_f32_16x16x32_bf16(
              af[mf][kk], bh2[nf][kk], acc[4 + mf][2 + nf], 0, 0, 0);
    __builtin_amdgcn_s_setprio(0);

    // ---- phase 3 ----
#pragma unroll
    for (int mf = 0; mf < 4; ++mf)
#pragma unroll
      for (int kk = 0; kk < 2; ++kk) {
        int row = wm * 128 + mf * 16 + l15;
        int ch = (kk * 4 + l4) ^ (row & 7);
        af[mf][kk] = *(const bf16x8*)&Asm[d][row * 64 + ch * 8];
      }
    if (st) { STGB(nb, j + 1, 2); STGB(nb, j + 1, 3); }
    __builtin_amdgcn_s_setprio(1);
#pragma unroll
    for (int mf = 0; mf < 4; ++mf)
#pragma unroll
      for (int nf = 0; nf < 2; ++nf)
#pragma unroll
        for (int kk = 0; kk < 2; ++kk)
          acc[mf][2 + nf] = __builtin_amdgcn_mfma_f32_16x16x32_bf16(
              af[mf][kk], bh2[nf][kk], acc[mf][2 + nf], 0, 0, 0);
    __builtin_amdgcn_s_setprio(0);
  }
#undef STGA
#undef STGB

#pragma unroll
  for (int mf = 0; mf < 8; ++mf)
#pragma unroll
    for (int nf = 0; nf < 4; ++nf) {
      int c = n0 + wn * 64 + nf * 16 + l15;
      float bv = bias[c];
      int r0 = m0 + wm * 128 + mf * 16 + l4 * 4;
#pragma unroll
      for (int r = 0; r < 4; ++r) {
        float val = acc[mf][nf][r] + bv;
        if (DO_RELU) val = fmaxf(val, 0.f);
        C[(size_t)(r0 + r) * Ndim + c] = (bf16)val;
      }
    }
}

// ---------------- 256-row MFMA GEMM, counted-vmcnt pipeline (R5-verified; N=1024 shapes) ----------------
template <int NFRAG, int DO_RELU>
__global__ __launch_bounds__(512, 2) void k_gemm256(const bf16* __restrict__ A,
                                                    const bf16* __restrict__ BT,
                                                    const float* __restrict__ bias,
                                                    bf16* __restrict__ C,
                                                    int Ndim, int Kdim) {
  __shared__ __align__(128) bf16 Asm[2][256 * 64];
  __shared__ __align__(128) bf16 Bsm[2][NFRAG * 64 * 64];
  const int tid = threadIdx.x;
  const int wid = tid >> 6, lane = tid & 63;
  const int l15 = lane & 15, l4 = lane >> 4;
  const int wm = wid >> 2, wn = wid & 3;

  const int gx = gridDim.x;
  int lin = blockIdx.y * gx + blockIdx.x;
  const int nwg = gx * gridDim.y;
  lin = (lin & 7) * (nwg >> 3) + (lin >> 3);
  const int m0 = (lin / gx) * 256;
  const int n0 = (lin % gx) * (NFRAG * 64);

  f32x4 acc[8][NFRAG];
#pragma unroll
  for (int mf = 0; mf < 8; ++mf)
#pragma unroll
    for (int nf = 0; nf < NFRAG; ++nf) acc[mf][nf] = f32x4{0.f, 0.f, 0.f, 0.f};

  const int lr = lane >> 3, lc = lane & 7;
  const int NT = Kdim >> 6;

#define STAGE(buf, t)                                                              \
  {                                                                                \
    _Pragma("unroll") for (int it = 0; it < 4; ++it) {                             \
      int r = it * 64 + wid * 8 + lr;                                              \
      int ch = lc ^ (r & 7);                                                       \
      glds16(A + (size_t)(m0 + r) * Kdim + (size_t)(t) * 64 + ch * 8,              \
             &Asm[buf][(it * 64 + wid * 8) * 64]);                                 \
    }                                                                              \
    _Pragma("unroll") for (int it = 0; it < NFRAG; ++it) {                         \
      int r = it * 64 + wid * 8 + lr;                                              \
      int ch = lc ^ (r & 7);                                                       \
      glds16(BT + (size_t)(n0 + r) * Kdim + (size_t)(t) * 64 + ch * 8,             \
             &Bsm[buf][(it * 64 + wid * 8) * 64]);                                 \
    }                                                                              \
  }

  int p = 0;
  STAGE(0, 0);
  for (int t = 0; t < NT; ++t) {
    if (t + 1 < NT) {
      STAGE(p ^ 1, t + 1);
      if constexpr (NFRAG == 4) asm volatile("s_waitcnt vmcnt(8)" ::: "memory");
      else                      asm volatile("s_waitcnt vmcnt(6)" ::: "memory");
    } else {
      asm volatile("s_waitcnt vmcnt(0)" ::: "memory");
    }
    __builtin_amdgcn_sched_barrier(0);
    __builtin_amdgcn_s_barrier();

    bf16x8 bfrag[NFRAG][2];
#pragma unroll
    for (int nf = 0; nf < NFRAG; ++nf)
#pragma unroll
      for (int kk = 0; kk < 2; ++kk) {
        int r = wn * (NFRAG * 16) + nf * 16 + l15;
        int ch = (kk * 4 + l4) ^ (r & 7);
        bfrag[nf][kk] = *(const bf16x8*)&Bsm[p][r * 64 + ch * 8];
      }
#pragma unroll
    for (int half = 0; half < 2; ++half) {
      bf16x8 afr[4][2];
#pragma unroll
      for (int mf4 = 0; mf4 < 4; ++mf4)
#pragma unroll
        for (int kk = 0; kk < 2; ++kk) {
          int r = wm * 128 + half * 64 + mf4 * 16 + l15;
          int ch = (kk * 4 + l4) ^ (r & 7);
          afr[mf4][kk] = *(const bf16x8*)&Asm[p][r * 64 + ch * 8];
        }
      __builtin_amdgcn_s_setprio(1);
#pragma unroll
      for (int mf4 = 0; mf4 < 4; ++mf4)
#pragma unroll
        for (int nf = 0; nf < NFRAG; ++nf)
#pragma unroll
          for (int kk = 0; kk < 2; ++kk)
            acc[half * 4 + mf4][nf] = __builtin_amdgcn_mfma_f32_16x16x32_bf16(
                afr[mf4][kk], bfrag[nf][kk], acc[half * 4 + mf4][nf], 0, 0, 0);
      __builtin_amdgcn_s_setprio(0);
    }
    __builtin_amdgcn_s_barrier();
    p ^= 1;
  }
#undef STAGE

#pragma unroll
  for (int mf = 0; mf < 8; ++mf)
#pragma unroll
    for (int nf = 0; nf < NFRAG; ++nf) {
      int c = n0 + wn * (NFRAG * 16) + nf * 16 + l15;
      float bv = bias[c];
      int r0 = m0 + wm * 128 + mf * 16 + l4 * 4;
#pragma unroll
      for (int r = 0; r < 4; ++r) {
        float val = acc[mf][nf][r] + bv;
        if (DO_RELU) val = fmaxf(val, 0.f);
        C[(size_t)(r0 + r) * Ndim + c] = (bf16)val;
      }
    }
}

// ---------------- flash attention, swapped-operand 32x32 MFMA, 8 waves/block ----------------
// R12-verified structure; P-frag build via v_permlane32_swap_b32 (VALU) instead of
// 4x shfl_xor(·,32) + 4x select per ks — removes DS-permute latency from the
// softmax->PV critical path.
__global__ __launch_bounds__(512) void k_attn(const bf16* __restrict__ q,
                                              const bf16* __restrict__ k,
                                              const bf16* __restrict__ vT,
                                              const int* __restrict__ mask,
                                              bf16* __restrict__ ctx, int qs) {
  __shared__ __align__(128) bf16 Kt[2][64 * 64];
  __shared__ __align__(128) bf16 Vt[2][64 * 64];
  __shared__ float Mb[Sn];
  const int tid = threadIdx.x, wid = tid >> 6, lane = tid & 63;
  const int q31 = lane & 31, hi = lane >> 5;

  int lin = blockIdx.y * gridDim.x + blockIdx.x;  // 512 blocks
  lin = (lin & 7) * 64 + (lin >> 3);
  const int qblk = lin & 7, bh = lin >> 3;
  const int b = bh >> 4, h = bh & 15;
  const int q0 = qblk * 256 + wid * 32;

  for (int i = tid; i < Sn; i += 512)
    Mb[i] = mask[b * Sn + i] ? 0.f : -1.44269504e9f;

  bf16x8 qf[4];
#pragma unroll
  for (int t = 0; t < 4; ++t)
    qf[t] = *(const bf16x8*)(q + (size_t)(b * Sn + q0 + q31) * qs + h * 64 +
                             t * 16 + hi * 8);

  f32x16 o[2];
  o[0] = {}; o[1] = {};
  float mr = -INFINITY, lr = 0.f;

  const int lrow = lane >> 3;
  const int lch0 = lane & 7;
  const int sch = lch0 ^ (lrow ^ (wid & 3));

  for (int kb = 0; kb < Sn / 64; ++kb) {
    const int cur = kb & 1;
    if (kb == 0) {
      int row = wid * 8 + lrow;
      glds16(k + (size_t)(b * Sn + row) * qs + h * 64 + sch * 8, &Kt[0][wid * 512]);
      glds16(vT + ((size_t)bh * 64 + row) * Sn + sch * 8, &Vt[0][wid * 512]);
      __syncthreads();
    }
    if (kb + 1 < Sn / 64) {
      int row = wid * 8 + lrow;
      glds16(k + (size_t)(b * Sn + (kb + 1) * 64 + row) * qs + h * 64 + sch * 8,
             &Kt[cur ^ 1][wid * 512]);
      glds16(vT + ((size_t)bh * 64 + row) * Sn + (kb + 1) * 64 + sch * 8,
             &Vt[cur ^ 1][wid * 512]);
    }

    f32x16 sc[2];
#pragma unroll
    for (int kf = 0; kf < 2; ++kf)
#pragma unroll
      for (int rg = 0; rg < 4; ++rg) {
        f32x4 mb4 = *(const f32x4*)&Mb[kb * 64 + kf * 32 + rg * 8 + 4 * hi];
#pragma unroll
        for (int j = 0; j < 4; ++j) sc[kf][rg * 4 + j] = mb4[j];
      }
#pragma unroll
    for (int t = 0; t < 4; ++t) {
#pragma unroll
      for (int kf = 0; kf < 2; ++kf) {
        int row = kf * 32 + q31;
        int ch = (t * 2 + hi) ^ ((row & 7) ^ ((row >> 3) & 3));
        bf16x8 kfr = *(const bf16x8*)&Kt[cur][row * 64 + ch * 8];
        sc[kf] = __builtin_amdgcn_mfma_f32_32x32x16_bf16(kfr, qf[t], sc[kf], 0, 0, 0);
      }
    }

    float rmax = fmaxf(sc[0][0], sc[0][1]);
#pragma unroll
    for (int i = 2; i < 16; i += 2)
      rmax = fmaxf(fmaxf(rmax, sc[0][i]), sc[0][i + 1]);
#pragma unroll
    for (int i = 0; i < 16; i += 2)
      rmax = fmaxf(fmaxf(rmax, sc[1][i]), sc[1][i + 1]);
    rmax = fmaxf(rmax, __shfl_xor(rmax, 32));

    if (!__all(rmax <= mr + 8.f)) {
      float mnew = fmaxf(mr, rmax);
      float psc = exp2fast(mr - mnew);
      mr = mnew;
      lr *= psc;
#pragma unroll
      for (int af = 0; af < 2; ++af)
#pragma unroll
        for (int i = 0; i < 16; ++i) o[af][i] *= psc;
    }

    float psum = 0.f;
#pragma unroll
    for (int kf = 0; kf < 2; ++kf)
#pragma unroll
      for (int i = 0; i < 16; ++i) {
        float p = exp2fast(sc[kf][i] - mr);
        sc[kf][i] = p;
        psum += p;
      }
    psum += __shfl_xor(psum, 32);
    lr += psum;

#pragma unroll
    for (int ks = 0; ks < 4; ++ks) {
      const int kf = ks >> 1, R = (ks & 1) * 8;
      unsigned int a0 = pkbf16(sc[kf][R + 0], sc[kf][R + 1]);
      unsigned int a1 = pkbf16(sc[kf][R + 2], sc[kf][R + 3]);
      unsigned int b0 = pkbf16(sc[kf][R + 4], sc[kf][R + 5]);
      unsigned int b1 = pkbf16(sc[kf][R + 6], sc[kf][R + 7]);
      // v_permlane32_swap_b32 x, y: x.hi <-> y.lo.  After swap(a0,b0):
      //   a0 = {a0.lo | b0.lo} = w0 (lo lanes: own a0; hi lanes: partner b0)
      //   b0 = {a0.hi | b0.hi} = w2 (lo lanes: partner a0; hi lanes: own b0)
      asm volatile("v_permlane32_swap_b32 %0, %1" : "+v"(a0), "+v"(b0));
      asm volatile("v_permlane32_swap_b32 %0, %1" : "+v"(a1), "+v"(b1));
      union { unsigned int w[4]; bf16x8 v; } pfu;
      pfu.w[0] = a0;
      pfu.w[1] = a1;
      pfu.w[2] = b0;
      pfu.w[3] = b1;
#pragma unroll
      for (int af = 0; af < 2; ++af) {
        int row = af * 32 + q31;
        int ch = (ks * 2 + hi) ^ ((row & 7) ^ ((row >> 3) & 3));
        bf16x8 vfr = *(const bf16x8*)&Vt[cur][row * 64 + ch * 8];
        o[af] = __builtin_amdgcn_mfma_f32_32x32x16_bf16(vfr, pfu.v, o[af], 0, 0, 0);
      }
    }
    __syncthreads();
  }

  float inv = 1.f / lr;
  const size_t cbase = (size_t)(b * Sn + q0 + q31) * Dn + h * 64;
#pragma unroll
  for (int af = 0; af < 2; ++af)
#pragma unroll
    for (int rg = 0; rg < 4; ++rg) {
      bf16x4 ov;
#pragma unroll
      for (int j = 0; j < 4; ++j) ov[j] = (bf16)(o[af][rg * 4 + j] * inv);
      *(bf16x4*)(ctx + cbase + af * 32 + rg * 8 + 4 * hi) = ov;
    }
}

// ---------------- residual + LayerNorm (ddof=1, /(std+eps)) ----------------
template <int XF32, int OUTF32>
__global__ __launch_bounds__(256) void k_ln(const void* __restrict__ xp,
                                            const bf16* __restrict__ res,
                                            const float* __restrict__ gamma,
                                            const float* __restrict__ beta,
                                            void* __restrict__ yout) {
  const int row = blockIdx.x, t = threadIdx.x;
  const size_t base = (size_t)row * Dn + t * 4;
  f32x4 a;
  if constexpr (XF32) {
    a = *(const f32x4*)((const float*)xp + base);
  } else {
    bf16x4 x4 = *(const bf16x4*)((const bf16*)xp + base);
#pragma unroll
    for (int j = 0; j < 4; ++j) a[j] = (float)x4[j];
  }
  bf16x4 rb = *(const bf16x4*)(res + base);
  f32x4 vv;
#pragma unroll
  for (int j = 0; j < 4; ++j) vv[j] = a[j] + (float)rb[j];

  float s = vv[0] + vv[1] + vv[2] + vv[3];
#pragma unroll
  for (int off = 32; off; off >>= 1) s += __shfl_xor(s, off);
  __shared__ float red1[4], red2[4];
  if ((t & 63) == 0) red1[t >> 6] = s;
  __syncthreads();
  float mean = (red1[0] + red1[1] + red1[2] + red1[3]) * (1.f / 1024.f);

  float d[4], s2 = 0.f;
#pragma unroll
  for (int j = 0; j < 4; ++j) { d[j] = vv[j] - mean; s2 += d[j] * d[j]; }
#pragma unroll
  for (int off = 32; off; off >>= 1) s2 += __shfl_xor(s2, off);
  if ((t & 63) == 0) red2[t >> 6] = s2;
  __syncthreads();
  float var = (red2[0] + red2[1] + red2[2] + red2[3]) * (1.f / 1023.f);
  float inv = 1.f / (sqrtf(var) + 1e-6f);

  f32x4 g = *(const f32x4*)(gamma + t * 4);
  f32x4 bt = *(const f32x4*)(beta + t * 4);
#pragma unroll
  for (int j = 0; j < 4; ++j) d[j] = g[j] * d[j] * inv + bt[j];
  if constexpr (OUTF32) {
    f32x4 outv = {d[0], d[1], d[2], d[3]};
    *(f32x4*)((float*)yout + base) = outv;
  } else {
    bf16x4 outb;
#pragma unroll
    for (int j = 0; j < 4; ++j) outb[j] = (bf16)d[j];
    *(bf16x4*)((bf16*)yout + base) = outb;
  }
}

// ---------------- host launcher ----------------
extern "C" void kernel_launch(void* const* d_in, const int* in_sizes, int n_in,
                              void* d_out, int out_size, void* d_ws, size_t ws_size,
                              hipStream_t stream) {
  const float* x   = (const float*)d_in[0];
  const int*   msk = (const int*)d_in[1];
  const float* Wq  = (const float*)d_in[2];
  const float* bq  = (const float*)d_in[3];
  const float* Wk  = (const float*)d_in[4];
  const float* bk  = (const float*)d_in[5];
  const float* Wv  = (const float*)d_in[6];
  const float* bv  = (const float*)d_in[7];
  const float* Wo  = (const float*)d_in[8];
  const float* bo  = (const float*)d_in[9];
  const float* W1  = (const float*)d_in[10];
  const float* b1  = (const float*)d_in[11];
  const float* W2  = (const float*)d_in[12];
  const float* b2  = (const float*)d_in[13];
  const float* g1  = (const float*)d_in[14];
  const float* be1 = (const float*)d_in[15];
  const float* g2  = (const float*)d_in[16];
  const float* be2 = (const float*)d_in[17];
  float* out = (float*)d_out;

  char* w = (char*)d_ws;
  size_t off = 0;
  auto alloc = [&](size_t bytes) { void* p = w + off; off += (bytes + 255) & ~(size_t)255; return p; };
  bf16* xb    = (bf16*)alloc((size_t)Mn * Dn * 2);
  bf16* wqkvT = (bf16*)alloc((size_t)QKVS * Dn * 2);
  bf16* woT   = (bf16*)alloc((size_t)Dn * Dn * 2);
  bf16* w1T   = (bf16*)alloc((size_t)Dn * DFFn * 2);
  bf16* w2T   = (bf16*)alloc((size_t)DFFn * Dn * 2);
  float* bqkv = (float*)alloc((size_t)QKVS * 4);
  bf16* qkv   = (bf16*)alloc((size_t)Mn * QKVS * 2);
  bf16* ctx   = (bf16*)alloc((size_t)Mn * Dn * 2);
  bf16* attnb = (bf16*)alloc((size_t)Mn * Dn * 2);
  bf16* yb    = (bf16*)alloc((size_t)Mn * Dn * 2);
  (void)ws_size; (void)in_sizes; (void)n_in; (void)out_size;
  bf16* vT = xb;
  bf16* hh = qkv;
  bf16* ff = xb;

  // 1. pack x; merged weight transposes (+perm) + bias concat
  k_cvt_bf16<<<(Mn * Dn) / 2048, 256, 0, stream>>>(x, xb);
  k_prep<<<12300, 256, 0, stream>>>(Wq, Wk, Wv, Wo, W1, W2, bq, bk, bv,
                                    wqkvT, woT, w1T, w2T, bqkv);

  // 2. fused QKV projection (8-phase, permuted B)
  k_gemm8ph<0><<<dim3(QKVS / 256, Mn / 256), 512, 0, stream>>>(xb, wqkvT, bqkv, qkv, QKVS, Dn);

  // 3. V transpose + flash attention
  k_vt<<<dim3(Sn / 64, Bn * Hn), 256, 0, stream>>>(qkv + 2048, vT, QKVS);
  k_attn<<<dim3(Sn / 256, Bn * Hn), 512, 0, stream>>>(qkv, qkv + 1024, vT, msk, ctx, QKVS);

  // 4. output projection
  k_gemm256<2, 0><<<dim3(Dn / 128, Mn / 256), 512, 0, stream>>>(ctx, woT, bo, attnb, Dn, Dn);

  // 5. LN1
  k_ln<1, 0><<<Mn, 256, 0, stream>>>(x, attnb, g1, be1, yb);

  // 6. FF1 (relu, 8-phase, permuted B)
  k_gemm8ph<1><<<dim3(DFFn / 256, Mn / 256), 512, 0, stream>>>(yb, w1T, b1, hh, DFFn, Dn);

  // 7. FF2
  k_gemm256<2, 0><<<dim3(Dn / 128, Mn / 256), 512, 0, stream>>>(hh, w2T, b2, ff, Dn, DFFn);

  // 8. LN2
  k_ln<0, 1><<<Mn, 256, 0, stream>>>(yb, ff, g2, be2, out);
}